// Round 10
// baseline (1011.431 us; speedup 1.0000x reference)
//
#include <hip/hip_runtime.h>
#include <hip/hip_bf16.h>

#define N_NODES_C 100000
#define N_EDGES_C 1600000
#define HID 128
#define OUTD 8
#define N_GRAPHS_C 128
#define NT 32   // nodes per block in gemm kernel
#define SEG 8   // pool segments per graph

typedef __attribute__((ext_vector_type(4))) float f4;
typedef __attribute__((ext_vector_type(4))) _Float16 h4;

static inline size_t align_up(size_t x, size_t a) { return (x + a - 1) & ~(a - 1); }

__device__ __forceinline__ f4 h2f(h4 v) { return __builtin_convertvector(v, f4); }
__device__ __forceinline__ h4 f2h(f4 v) { return __builtin_convertvector(v, h4); }

__global__ __launch_bounds__(256) void k_cvt(const float* __restrict__ in,
                                             _Float16* __restrict__ out) {
    int i = blockIdx.x * blockDim.x + threadIdx.x;
    f4 v = *(const f4*)(in + (size_t)i * 4);
    *(h4*)(out + (size_t)i * 4) = f2h(v);
}

__global__ void k_zero_counts(int* __restrict__ counts, int n) {
    int i = blockIdx.x * blockDim.x + threadIdx.x;
    if (i < n) counts[i] = 0;
}

__global__ void k_count(const int* __restrict__ dst, int* __restrict__ counts) {
    int stride = gridDim.x * blockDim.x;
    for (int e = blockIdx.x * blockDim.x + threadIdx.x; e < N_EDGES_C; e += stride)
        atomicAdd(&counts[dst[e]], 1);
}

__global__ void k_scan1(const int* __restrict__ counts, int* __restrict__ offsets,
                        int* __restrict__ partials) {
    __shared__ int s[256];
    int tid = threadIdx.x;
    int i = blockIdx.x * 256 + tid;
    int v = (i < N_NODES_C) ? counts[i] : 0;
    s[tid] = v;
    __syncthreads();
    for (int off = 1; off < 256; off <<= 1) {
        int t = (tid >= off) ? s[tid - off] : 0;
        __syncthreads();
        s[tid] += t;
        __syncthreads();
    }
    if (i < N_NODES_C) offsets[i] = s[tid] - v;
    if (tid == 255) partials[blockIdx.x] = s[255];
}

__global__ void k_scan2(int* __restrict__ partials, int nb) {
    __shared__ int s[512];
    int tid = threadIdx.x;
    int v = (tid < nb) ? partials[tid] : 0;
    s[tid] = v;
    __syncthreads();
    for (int off = 1; off < 512; off <<= 1) {
        int t = (tid >= off) ? s[tid - off] : 0;
        __syncthreads();
        s[tid] += t;
        __syncthreads();
    }
    if (tid < nb) partials[tid] = s[tid] - v;
}

__global__ void k_scan3(int* __restrict__ offsets, const int* __restrict__ partials,
                        int* __restrict__ cursor) {
    int i = blockIdx.x * blockDim.x + threadIdx.x;
    if (i < N_NODES_C) {
        int o = offsets[i] + partials[i >> 8];
        offsets[i] = o;
        cursor[i] = o;
    }
    if (i == 0) offsets[N_NODES_C] = N_EDGES_C;
}

__global__ void k_fill(const int* __restrict__ src, const int* __restrict__ dst,
                       int* __restrict__ cursor, int* __restrict__ es) {
    int stride = gridDim.x * blockDim.x;
    for (int e = blockIdx.x * blockDim.x + threadIdx.x; e < N_EDGES_C; e += stride) {
        int d = dst[e];
        int pos = atomicAdd(&cursor[d], 1);
        es[pos] = src[e];
    }
}

// Gather-sum: one 32-lane group per node. No LDS, no barriers -> max TLP.
// agg[node][:] = sum_{e in CSR[node]} h_in[es[e]][:]  (fp16 in, fp32 out)
__global__ __launch_bounds__(256) void k_gather(
    const _Float16* __restrict__ h_in, float* __restrict__ agg,
    const int* __restrict__ offsets, const int* __restrict__ es) {
    const int node = (blockIdx.x << 3) + (threadIdx.x >> 5);  // 8 groups/block
    const int lane = threadIdx.x & 31;
    const int c4 = lane * 4;
    const int beg = offsets[node];
    const int end = offsets[node + 1];
    f4 a0 = {0.f, 0.f, 0.f, 0.f}, a1 = a0, a2 = a0, a3 = a0;
    f4 a4 = a0, a5 = a0, a6 = a0, a7 = a0;
    int e = beg;
    for (; e + 8 <= end; e += 8) {
        int s0 = es[e],     s1 = es[e + 1], s2 = es[e + 2], s3 = es[e + 3];
        int s4 = es[e + 4], s5 = es[e + 5], s6 = es[e + 6], s7 = es[e + 7];
        h4 v0 = *(const h4*)(h_in + (size_t)s0 * HID + c4);
        h4 v1 = *(const h4*)(h_in + (size_t)s1 * HID + c4);
        h4 v2 = *(const h4*)(h_in + (size_t)s2 * HID + c4);
        h4 v3 = *(const h4*)(h_in + (size_t)s3 * HID + c4);
        h4 v4 = *(const h4*)(h_in + (size_t)s4 * HID + c4);
        h4 v5 = *(const h4*)(h_in + (size_t)s5 * HID + c4);
        h4 v6 = *(const h4*)(h_in + (size_t)s6 * HID + c4);
        h4 v7 = *(const h4*)(h_in + (size_t)s7 * HID + c4);
        a0 += h2f(v0); a1 += h2f(v1); a2 += h2f(v2); a3 += h2f(v3);
        a4 += h2f(v4); a5 += h2f(v5); a6 += h2f(v6); a7 += h2f(v7);
    }
    for (; e + 4 <= end; e += 4) {
        int s0 = es[e], s1 = es[e + 1], s2 = es[e + 2], s3 = es[e + 3];
        h4 v0 = *(const h4*)(h_in + (size_t)s0 * HID + c4);
        h4 v1 = *(const h4*)(h_in + (size_t)s1 * HID + c4);
        h4 v2 = *(const h4*)(h_in + (size_t)s2 * HID + c4);
        h4 v3 = *(const h4*)(h_in + (size_t)s3 * HID + c4);
        a0 += h2f(v0); a1 += h2f(v1); a2 += h2f(v2); a3 += h2f(v3);
    }
    for (; e < end; ++e)
        a0 += h2f(*(const h4*)(h_in + (size_t)es[e] * HID + c4));
    *(f4*)(agg + (size_t)node * HID + c4) =
        ((a0 + a1) + (a2 + a3)) + ((a4 + a5) + (a6 + a7));
}

// GEMM: h_out = atan(agg @ W_rel + b_rel + h_in @ W_root), fp16 out.
// No LDS: A/H via L1-resident broadcast loads, W streams L2-resident.
__global__ __launch_bounds__(256) void k_gemm(
    const float* __restrict__ agg, const _Float16* __restrict__ h_in,
    _Float16* __restrict__ h_out,
    const float* __restrict__ W_rel, const float* __restrict__ b_rel,
    const float* __restrict__ W_root) {
    const int tid = threadIdx.x;
    const int node0 = blockIdx.x * NT;
    const int jt = tid & 31;
    const int it = tid >> 5;  // 0..7
    const int j0 = jt * 4;
    const int i0 = it * 4;
    const float*    aP = agg  + (size_t)(node0 + i0) * HID;
    const _Float16* hP = h_in + (size_t)(node0 + i0) * HID;

    f4 acc0 = {0.f, 0.f, 0.f, 0.f}, acc1 = acc0, acc2 = acc0, acc3 = acc0;
    for (int k4 = 0; k4 < HID; k4 += 4) {
        const f4 A0 = *(const f4*)(aP + 0 * HID + k4);
        const f4 A1 = *(const f4*)(aP + 1 * HID + k4);
        const f4 A2 = *(const f4*)(aP + 2 * HID + k4);
        const f4 A3 = *(const f4*)(aP + 3 * HID + k4);
        const f4 H0 = h2f(*(const h4*)(hP + 0 * HID + k4));
        const f4 H1 = h2f(*(const h4*)(hP + 1 * HID + k4));
        const f4 H2 = h2f(*(const h4*)(hP + 2 * HID + k4));
        const f4 H3 = h2f(*(const h4*)(hP + 3 * HID + k4));
#pragma unroll
        for (int kk = 0; kk < 4; ++kk) {
            const int k = k4 + kk;
            const f4 wr = *(const f4*)&W_rel[k * HID + j0];
            const f4 wo = *(const f4*)&W_root[k * HID + j0];
            acc0 += A0[kk] * wr + H0[kk] * wo;
            acc1 += A1[kk] * wr + H1[kk] * wo;
            acc2 += A2[kk] * wr + H2[kk] * wo;
            acc3 += A3[kk] * wr + H3[kk] * wo;
        }
    }
    const f4 b4 = *(const f4*)&b_rel[j0];
    acc0 += b4; acc1 += b4; acc2 += b4; acc3 += b4;
    f4 r0, r1, r2, r3;
#pragma unroll
    for (int c = 0; c < 4; ++c) {
        r0[c] = atanf(acc0[c]);
        r1[c] = atanf(acc1[c]);
        r2[c] = atanf(acc2[c]);
        r3[c] = atanf(acc3[c]);
    }
    *(h4*)(h_out + (size_t)(node0 + i0 + 0) * HID + j0) = f2h(r0);
    *(h4*)(h_out + (size_t)(node0 + i0 + 1) * HID + j0) = f2h(r1);
    *(h4*)(h_out + (size_t)(node0 + i0 + 2) * HID + j0) = f2h(r2);
    *(h4*)(h_out + (size_t)(node0 + i0 + 3) * HID + j0) = f2h(r3);
}

// Pool stage 1: per (graph, segment) partial sums over fp16 h -> fp32 part
__global__ __launch_bounds__(256) void k_pool1(
    const _Float16* __restrict__ h, const int* __restrict__ batch,
    float* __restrict__ part) {
    __shared__ float sm[2][HID];
    const int b = blockIdx.x;
    const int g = b >> 3, s = b & (SEG - 1);
    const int j = threadIdx.x & 127;
    const int half = threadIdx.x >> 7;

    int lo = 0, hi = N_NODES_C;
    while (lo < hi) { int mid = (lo + hi) >> 1; if (batch[mid] < g) lo = mid + 1; else hi = mid; }
    int start = lo;
    hi = N_NODES_C;
    while (lo < hi) { int mid = (lo + hi) >> 1; if (batch[mid] < g + 1) lo = mid + 1; else hi = mid; }
    int end = lo;
    int len = end - start;
    int s0 = start + (int)((long long)len * s / SEG);
    int s1 = start + (int)((long long)len * (s + 1) / SEG);

    float acc = 0.f;
    for (int i = s0 + half; i < s1; i += 2) acc += (float)h[(size_t)i * HID + j];
    sm[half][j] = acc;
    __syncthreads();
    if (threadIdx.x < HID) part[(size_t)b * HID + j] = sm[0][j] + sm[1][j];
}

// Pool stage 2 + head
__global__ __launch_bounds__(128) void k_head(
    const float* __restrict__ part, const float* __restrict__ W_out,
    const float* __restrict__ b_out, float* __restrict__ out) {
    __shared__ float sf[HID];
    const int g = blockIdx.x;
    const int j = threadIdx.x;
    float v = 0.f;
    for (int s = 0; s < SEG; ++s) v += part[(size_t)(g * SEG + s) * HID + j];
    sf[j] = v;
    __syncthreads();
    if (j < OUTD) {
        float a = b_out[j];
        for (int k = 0; k < HID; ++k) a += sf[k] * W_out[k * OUTD + j];
        out[g * OUTD + j] = 1.f / (1.f + expf(-a));
    }
}

extern "C" void kernel_launch(void* const* d_in, const int* in_sizes, int n_in,
                              void* d_out, int out_size, void* d_ws, size_t ws_size,
                              hipStream_t stream) {
    const float* x      = (const float*)d_in[0];
    const int*   ei     = (const int*)d_in[1];
    const int*   src    = ei;
    const int*   dst    = ei + N_EDGES_C;
    const int*   batch  = (const int*)d_in[2];
    const float* W_rel  = (const float*)d_in[3];
    const float* b_rel  = (const float*)d_in[4];
    const float* W_root = (const float*)d_in[5];
    const float* W_out  = (const float*)d_in[6];
    const float* b_out  = (const float*)d_in[7];
    float* out = (float*)d_out;

    char* ws = (char*)d_ws;
    size_t off = 0;
    auto alloc = [&](size_t bytes) { void* p = ws + off; off = align_up(off + bytes, 256); return p; };
    _Float16* xh   = (_Float16*)alloc((size_t)N_NODES_C * HID * 2);  // x fp16; reused as h2
    _Float16* h1h  = (_Float16*)alloc((size_t)N_NODES_C * HID * 2);  // h1 fp16; reused as h3
    float* aggf    = (float*)alloc((size_t)N_NODES_C * HID * sizeof(float));
    int*   offsets = (int*)alloc((size_t)(N_NODES_C + 1) * sizeof(int));
    int*   cursor  = (int*)alloc((size_t)N_NODES_C * sizeof(int));
    int*   partials= (int*)alloc(512 * sizeof(int));
    int*   es      = (int*)alloc((size_t)N_EDGES_C * sizeof(int));
    float* part    = (float*)alloc((size_t)N_GRAPHS_C * SEG * HID * sizeof(float));

    const int nb_nodes = (N_NODES_C + 255) / 256;  // 391
    const int gather_blocks = N_NODES_C / 8;       // 12500 (8 node-groups/block)
    const int gemm_blocks = N_NODES_C / NT;        // 3125
    const int WSZ = HID * HID;

    // ---- x -> fp16 ----
    k_cvt<<<(N_NODES_C * HID) / 4 / 256, 256, 0, stream>>>(x, xh);

    // ---- CSR build (counts live in `cursor`) ----
    k_zero_counts<<<nb_nodes, 256, 0, stream>>>(cursor, N_NODES_C);
    k_count<<<2048, 256, 0, stream>>>(dst, cursor);
    k_scan1<<<nb_nodes, 256, 0, stream>>>(cursor, offsets, partials);
    k_scan2<<<1, 512, 0, stream>>>(partials, nb_nodes);
    k_scan3<<<nb_nodes, 256, 0, stream>>>(offsets, partials, cursor);
    k_fill<<<2048, 256, 0, stream>>>(src, dst, cursor, es);

    // ---- 3 GraphConv layers: gather (latency-opt) + gemm (VALU-opt) ----
    k_gather<<<gather_blocks, 256, 0, stream>>>(xh, aggf, offsets, es);
    k_gemm<<<gemm_blocks, 256, 0, stream>>>(aggf, xh, h1h,
                                            W_rel + 0 * WSZ, b_rel + 0 * HID, W_root + 0 * WSZ);
    k_gather<<<gather_blocks, 256, 0, stream>>>(h1h, aggf, offsets, es);
    k_gemm<<<gemm_blocks, 256, 0, stream>>>(aggf, h1h, xh,
                                            W_rel + 1 * WSZ, b_rel + 1 * HID, W_root + 1 * WSZ);
    k_gather<<<gather_blocks, 256, 0, stream>>>(xh, aggf, offsets, es);
    k_gemm<<<gemm_blocks, 256, 0, stream>>>(aggf, xh, h1h,
                                            W_rel + 2 * WSZ, b_rel + 2 * HID, W_root + 2 * WSZ);

    // ---- pool + head ----
    k_pool1<<<N_GRAPHS_C * SEG, 256, 0, stream>>>(h1h, batch, part);
    k_head<<<N_GRAPHS_C, 128, 0, stream>>>(part, W_out, b_out, out);
}

// Round 11
// 709.584 us; speedup vs baseline: 1.4254x; 1.4254x over previous
//
#include <hip/hip_runtime.h>
#include <hip/hip_bf16.h>

#define N_NODES_C 100000
#define N_EDGES_C 1600000
#define HID 128
#define OUTD 8
#define N_GRAPHS_C 128
#define SEG 8   // pool segments per graph

typedef __attribute__((ext_vector_type(4))) float f4;
typedef __attribute__((ext_vector_type(4))) _Float16 h4;
typedef __attribute__((ext_vector_type(8))) _Float16 f16x8;
typedef __attribute__((ext_vector_type(4))) float f32x4;

static inline size_t align_up(size_t x, size_t a) { return (x + a - 1) & ~(a - 1); }

__device__ __forceinline__ f4 h2f(h4 v) { return __builtin_convertvector(v, f4); }
__device__ __forceinline__ h4 f2h(f4 v) { return __builtin_convertvector(v, h4); }

__global__ __launch_bounds__(256) void k_cvt(const float* __restrict__ in,
                                             _Float16* __restrict__ out) {
    int i = blockIdx.x * blockDim.x + threadIdx.x;
    f4 v = *(const f4*)(in + (size_t)i * 4);
    *(h4*)(out + (size_t)i * 4) = f2h(v);
}

// Build wT fp16 [L][2][j][k] from W_rel/W_root fp32 [L][k][j]
__global__ __launch_bounds__(128) void k_wprep(
    const float* __restrict__ W_rel, const float* __restrict__ W_root,
    _Float16* __restrict__ wT) {
    const int b = blockIdx.x;      // 0..767: l = b>>8, m = (b>>7)&1, j = b&127
    const int l = b >> 8;
    const int m = (b >> 7) & 1;
    const int j = b & 127;
    const int k = threadIdx.x;
    const float* W = (m == 0 ? W_rel : W_root) + (size_t)l * HID * HID;
    wT[(((size_t)l * 2 + m) * HID + j) * HID + k] = (_Float16)W[k * HID + j];
}

__global__ void k_zero_counts(int* __restrict__ counts, int n) {
    int i = blockIdx.x * blockDim.x + threadIdx.x;
    if (i < n) counts[i] = 0;
}

__global__ void k_count(const int* __restrict__ dst, int* __restrict__ counts) {
    int stride = gridDim.x * blockDim.x;
    for (int e = blockIdx.x * blockDim.x + threadIdx.x; e < N_EDGES_C; e += stride)
        atomicAdd(&counts[dst[e]], 1);
}

__global__ void k_scan1(const int* __restrict__ counts, int* __restrict__ offsets,
                        int* __restrict__ partials) {
    __shared__ int s[256];
    int tid = threadIdx.x;
    int i = blockIdx.x * 256 + tid;
    int v = (i < N_NODES_C) ? counts[i] : 0;
    s[tid] = v;
    __syncthreads();
    for (int off = 1; off < 256; off <<= 1) {
        int t = (tid >= off) ? s[tid - off] : 0;
        __syncthreads();
        s[tid] += t;
        __syncthreads();
    }
    if (i < N_NODES_C) offsets[i] = s[tid] - v;
    if (tid == 255) partials[blockIdx.x] = s[255];
}

__global__ void k_scan2(int* __restrict__ partials, int nb) {
    __shared__ int s[512];
    int tid = threadIdx.x;
    int v = (tid < nb) ? partials[tid] : 0;
    s[tid] = v;
    __syncthreads();
    for (int off = 1; off < 512; off <<= 1) {
        int t = (tid >= off) ? s[tid - off] : 0;
        __syncthreads();
        s[tid] += t;
        __syncthreads();
    }
    if (tid < nb) partials[tid] = s[tid] - v;
}

__global__ void k_scan3(int* __restrict__ offsets, const int* __restrict__ partials,
                        int* __restrict__ cursor) {
    int i = blockIdx.x * blockDim.x + threadIdx.x;
    if (i < N_NODES_C) {
        int o = offsets[i] + partials[i >> 8];
        offsets[i] = o;
        cursor[i] = o;
    }
    if (i == 0) offsets[N_NODES_C] = N_EDGES_C;
}

__global__ void k_fill(const int* __restrict__ src, const int* __restrict__ dst,
                       int* __restrict__ cursor, int* __restrict__ es) {
    int stride = gridDim.x * blockDim.x;
    for (int e = blockIdx.x * blockDim.x + threadIdx.x; e < N_EDGES_C; e += stride) {
        int d = dst[e];
        int pos = atomicAdd(&cursor[d], 1);
        es[pos] = src[e];
    }
}

// Gather-sum: one 32-lane group per node. No LDS, no barriers -> max TLP.
// agg[node][:] = sum_{e in CSR[node]} h_in[es[e]][:]  (fp16 in, fp32 acc, fp16 out)
__global__ __launch_bounds__(256) void k_gather(
    const _Float16* __restrict__ h_in, _Float16* __restrict__ agg,
    const int* __restrict__ offsets, const int* __restrict__ es) {
    const int node = (blockIdx.x << 3) + (threadIdx.x >> 5);  // 8 groups/block
    const int lane = threadIdx.x & 31;
    const int c4 = lane * 4;
    const int beg = offsets[node];
    const int end = offsets[node + 1];
    f4 a0 = {0.f, 0.f, 0.f, 0.f}, a1 = a0, a2 = a0, a3 = a0;
    f4 a4 = a0, a5 = a0, a6 = a0, a7 = a0;
    int e = beg;
    for (; e + 8 <= end; e += 8) {
        int s0 = es[e],     s1 = es[e + 1], s2 = es[e + 2], s3 = es[e + 3];
        int s4 = es[e + 4], s5 = es[e + 5], s6 = es[e + 6], s7 = es[e + 7];
        h4 v0 = *(const h4*)(h_in + (size_t)s0 * HID + c4);
        h4 v1 = *(const h4*)(h_in + (size_t)s1 * HID + c4);
        h4 v2 = *(const h4*)(h_in + (size_t)s2 * HID + c4);
        h4 v3 = *(const h4*)(h_in + (size_t)s3 * HID + c4);
        h4 v4 = *(const h4*)(h_in + (size_t)s4 * HID + c4);
        h4 v5 = *(const h4*)(h_in + (size_t)s5 * HID + c4);
        h4 v6 = *(const h4*)(h_in + (size_t)s6 * HID + c4);
        h4 v7 = *(const h4*)(h_in + (size_t)s7 * HID + c4);
        a0 += h2f(v0); a1 += h2f(v1); a2 += h2f(v2); a3 += h2f(v3);
        a4 += h2f(v4); a5 += h2f(v5); a6 += h2f(v6); a7 += h2f(v7);
    }
    for (; e + 4 <= end; e += 4) {
        int s0 = es[e], s1 = es[e + 1], s2 = es[e + 2], s3 = es[e + 3];
        h4 v0 = *(const h4*)(h_in + (size_t)s0 * HID + c4);
        h4 v1 = *(const h4*)(h_in + (size_t)s1 * HID + c4);
        h4 v2 = *(const h4*)(h_in + (size_t)s2 * HID + c4);
        h4 v3 = *(const h4*)(h_in + (size_t)s3 * HID + c4);
        a0 += h2f(v0); a1 += h2f(v1); a2 += h2f(v2); a3 += h2f(v3);
    }
    for (; e < end; ++e)
        a0 += h2f(*(const h4*)(h_in + (size_t)es[e] * HID + c4));
    f4 t = ((a0 + a1) + (a2 + a3)) + ((a4 + a5) + (a6 + a7));
    *(h4*)(agg + (size_t)node * HID + c4) = f2h(t);
}

// MFMA GEMM: h_out = atan(agg @ W_rel + b_rel + h_in @ W_root), all fp16 operands.
// Per wave: 16 nodes x 16 j, 4 k-steps, 2 chained MFMAs per step.
// A layout (m92-verified pattern): row = lane&15, k = (lane>>4)*8 + [0..7] contiguous.
// B from wT[j][k] ("B^T input"): col j = lane&15, same k mapping.
// C/D (m89-verified): col = lane&15, row = (lane>>4)*4 + reg.
__global__ __launch_bounds__(256) void k_gemm_mfma(
    const _Float16* __restrict__ agg, const _Float16* __restrict__ h_in,
    _Float16* __restrict__ h_out,
    const _Float16* __restrict__ wT,   // [2][HID][HID] (j,k) for this layer
    const float* __restrict__ b_rel) {
    const int wave = (blockIdx.x << 2) + (threadIdx.x >> 6);  // 0..49999
    const int lane = threadIdx.x & 63;
    const int ntile = wave >> 3;   // 0..6249
    const int jt = wave & 7;       // 0..7
    const int row = lane & 15;
    const int kg = lane >> 4;      // 0..3
    const int node0 = ntile << 4;
    const int j0 = jt << 4;

    const _Float16* aP  = agg  + (size_t)(node0 + row) * HID + (kg << 3);
    const _Float16* hP  = h_in + (size_t)(node0 + row) * HID + (kg << 3);
    const _Float16* wrP = wT + (size_t)(j0 + row) * HID + (kg << 3);            // W_rel^T
    const _Float16* woP = wT + (size_t)(HID + j0 + row) * HID + (kg << 3);      // W_root^T

    f32x4 acc = {0.f, 0.f, 0.f, 0.f};
#pragma unroll
    for (int ks = 0; ks < 4; ++ks) {
        const int ko = ks * 32;
        f16x8 aA = *(const f16x8*)(aP + ko);
        f16x8 aH = *(const f16x8*)(hP + ko);
        f16x8 bR = *(const f16x8*)(wrP + ko);
        f16x8 bO = *(const f16x8*)(woP + ko);
        acc = __builtin_amdgcn_mfma_f32_16x16x32_f16(aA, bR, acc, 0, 0, 0);
        acc = __builtin_amdgcn_mfma_f32_16x16x32_f16(aH, bO, acc, 0, 0, 0);
    }
    const int j = j0 + row;
    const float b = b_rel[j];
#pragma unroll
    for (int r = 0; r < 4; ++r) {
        float v = atanf(acc[r] + b);
        h_out[(size_t)(node0 + (kg << 2) + r) * HID + j] = (_Float16)v;
    }
}

// Pool stage 1: per (graph, segment) partial sums over fp16 h -> fp32 part
__global__ __launch_bounds__(256) void k_pool1(
    const _Float16* __restrict__ h, const int* __restrict__ batch,
    float* __restrict__ part) {
    __shared__ float sm[2][HID];
    const int b = blockIdx.x;
    const int g = b >> 3, s = b & (SEG - 1);
    const int j = threadIdx.x & 127;
    const int half = threadIdx.x >> 7;

    int lo = 0, hi = N_NODES_C;
    while (lo < hi) { int mid = (lo + hi) >> 1; if (batch[mid] < g) lo = mid + 1; else hi = mid; }
    int start = lo;
    hi = N_NODES_C;
    while (lo < hi) { int mid = (lo + hi) >> 1; if (batch[mid] < g + 1) lo = mid + 1; else hi = mid; }
    int end = lo;
    int len = end - start;
    int s0 = start + (int)((long long)len * s / SEG);
    int s1 = start + (int)((long long)len * (s + 1) / SEG);

    float acc = 0.f;
    for (int i = s0 + half; i < s1; i += 2) acc += (float)h[(size_t)i * HID + j];
    sm[half][j] = acc;
    __syncthreads();
    if (threadIdx.x < HID) part[(size_t)b * HID + j] = sm[0][j] + sm[1][j];
}

// Pool stage 2 + head
__global__ __launch_bounds__(128) void k_head(
    const float* __restrict__ part, const float* __restrict__ W_out,
    const float* __restrict__ b_out, float* __restrict__ out) {
    __shared__ float sf[HID];
    const int g = blockIdx.x;
    const int j = threadIdx.x;
    float v = 0.f;
    for (int s = 0; s < SEG; ++s) v += part[(size_t)(g * SEG + s) * HID + j];
    sf[j] = v;
    __syncthreads();
    if (j < OUTD) {
        float a = b_out[j];
        for (int k = 0; k < HID; ++k) a += sf[k] * W_out[k * OUTD + j];
        out[g * OUTD + j] = 1.f / (1.f + expf(-a));
    }
}

extern "C" void kernel_launch(void* const* d_in, const int* in_sizes, int n_in,
                              void* d_out, int out_size, void* d_ws, size_t ws_size,
                              hipStream_t stream) {
    const float* x      = (const float*)d_in[0];
    const int*   ei     = (const int*)d_in[1];
    const int*   src    = ei;
    const int*   dst    = ei + N_EDGES_C;
    const int*   batch  = (const int*)d_in[2];
    const float* W_rel  = (const float*)d_in[3];
    const float* b_rel  = (const float*)d_in[4];
    const float* W_root = (const float*)d_in[5];
    const float* W_out  = (const float*)d_in[6];
    const float* b_out  = (const float*)d_in[7];
    float* out = (float*)d_out;

    char* ws = (char*)d_ws;
    size_t off = 0;
    auto alloc = [&](size_t bytes) { void* p = ws + off; off = align_up(off + bytes, 256); return p; };
    _Float16* xh    = (_Float16*)alloc((size_t)N_NODES_C * HID * 2);  // x fp16; reused as h2
    _Float16* h1h   = (_Float16*)alloc((size_t)N_NODES_C * HID * 2);  // h1 fp16; reused as h3
    _Float16* agg16 = (_Float16*)alloc((size_t)N_NODES_C * HID * 2);
    _Float16* wT    = (_Float16*)alloc((size_t)3 * 2 * HID * HID * 2);
    int*   offsets = (int*)alloc((size_t)(N_NODES_C + 1) * sizeof(int));
    int*   cursor  = (int*)alloc((size_t)N_NODES_C * sizeof(int));
    int*   partials= (int*)alloc(512 * sizeof(int));
    int*   es      = (int*)alloc((size_t)N_EDGES_C * sizeof(int));
    float* part    = (float*)alloc((size_t)N_GRAPHS_C * SEG * HID * sizeof(float));

    const int nb_nodes = (N_NODES_C + 255) / 256;  // 391
    const int gather_blocks = N_NODES_C / 8;       // 12500
    const int mfma_blocks = (N_NODES_C / 16) * 8 / 4;  // 6250 ntiles * 8 jtiles / 4 waves = 12500
    const size_t WTL = (size_t)2 * HID * HID;      // wT elems per layer

    // ---- weight prep + x -> fp16 ----
    k_wprep<<<768, 128, 0, stream>>>(W_rel, W_root, wT);
    k_cvt<<<(N_NODES_C * HID) / 4 / 256, 256, 0, stream>>>(x, xh);

    // ---- CSR build (counts live in `cursor`) ----
    k_zero_counts<<<nb_nodes, 256, 0, stream>>>(cursor, N_NODES_C);
    k_count<<<2048, 256, 0, stream>>>(dst, cursor);
    k_scan1<<<nb_nodes, 256, 0, stream>>>(cursor, offsets, partials);
    k_scan2<<<1, 512, 0, stream>>>(partials, nb_nodes);
    k_scan3<<<nb_nodes, 256, 0, stream>>>(offsets, partials, cursor);
    k_fill<<<2048, 256, 0, stream>>>(src, dst, cursor, es);

    // ---- 3 GraphConv layers: gather (latency-opt) + MFMA gemm ----
    k_gather<<<gather_blocks, 256, 0, stream>>>(xh, agg16, offsets, es);
    k_gemm_mfma<<<mfma_blocks, 256, 0, stream>>>(agg16, xh, h1h, wT + 0 * WTL, b_rel + 0 * HID);
    k_gather<<<gather_blocks, 256, 0, stream>>>(h1h, agg16, offsets, es);
    k_gemm_mfma<<<mfma_blocks, 256, 0, stream>>>(agg16, h1h, xh, wT + 1 * WTL, b_rel + 1 * HID);
    k_gather<<<gather_blocks, 256, 0, stream>>>(xh, agg16, offsets, es);
    k_gemm_mfma<<<mfma_blocks, 256, 0, stream>>>(agg16, xh, h1h, wT + 2 * WTL, b_rel + 2 * HID);

    // ---- pool + head ----
    k_pool1<<<N_GRAPHS_C * SEG, 256, 0, stream>>>(h1h, batch, part);
    k_head<<<N_GRAPHS_C, 128, 0, stream>>>(part, W_out, b_out, out);
}

// Round 12
// 570.209 us; speedup vs baseline: 1.7738x; 1.2444x over previous
//
#include <hip/hip_runtime.h>
#include <hip/hip_bf16.h>

#define N_NODES_C 100000
#define N_EDGES_C 1600000
#define HID 128
#define OUTD 8
#define N_GRAPHS_C 128
#define SEG 8     // pool segments per graph
#define NBUCK 256 // CSR sort buckets
#define BSZ 391   // nodes per bucket (256*391 = 100096 >= 100000)
#define BCAP 8192 // LDS capacity per bucket in k_sort2 (edges/bucket ~6250+-80)
#define CHUNK 2048
#define EPT 8     // edges per thread in k_scatter1

typedef __attribute__((ext_vector_type(4))) float f4;
typedef __attribute__((ext_vector_type(4))) _Float16 h4;
typedef __attribute__((ext_vector_type(8))) _Float16 f16x8;
typedef __attribute__((ext_vector_type(4))) float f32x4;

static inline size_t align_up(size_t x, size_t a) { return (x + a - 1) & ~(a - 1); }

__device__ __forceinline__ f4 h2f(h4 v) { return __builtin_convertvector(v, f4); }
__device__ __forceinline__ h4 f2h(f4 v) { return __builtin_convertvector(v, h4); }

__global__ __launch_bounds__(256) void k_cvt(const float* __restrict__ in,
                                             _Float16* __restrict__ out) {
    int i = blockIdx.x * blockDim.x + threadIdx.x;
    f4 v = *(const f4*)(in + (size_t)i * 4);
    *(h4*)(out + (size_t)i * 4) = f2h(v);
}

// Build wT fp16 [L][2][j][k] from W_rel/W_root fp32 [L][k][j]
__global__ __launch_bounds__(128) void k_wprep(
    const float* __restrict__ W_rel, const float* __restrict__ W_root,
    _Float16* __restrict__ wT) {
    const int b = blockIdx.x;      // l = b>>8, m = (b>>7)&1, j = b&127
    const int l = b >> 8;
    const int m = (b >> 7) & 1;
    const int j = b & 127;
    const int k = threadIdx.x;
    const float* W = (m == 0 ? W_rel : W_root) + (size_t)l * HID * HID;
    wT[(((size_t)l * 2 + m) * HID + j) * HID + k] = (_Float16)W[k * HID + j];
}

// ==================== CSR build: 2-pass LDS-staged bucket sort ====================

__global__ __launch_bounds__(256) void k_zeroB(int* __restrict__ b) { b[threadIdx.x] = 0; }

// Pass 0: global bucket histogram (LDS-privatized)
__global__ __launch_bounds__(256) void k_hist1(const int* __restrict__ dst,
                                               int* __restrict__ bhist) {
    __shared__ int h[NBUCK];
    h[threadIdx.x] = 0;
    __syncthreads();
    int stride = gridDim.x * blockDim.x;
    for (int e = blockIdx.x * 256 + threadIdx.x; e < N_EDGES_C; e += stride)
        atomicAdd(&h[dst[e] / BSZ], 1);
    __syncthreads();
    if (h[threadIdx.x]) atomicAdd(&bhist[threadIdx.x], h[threadIdx.x]);
}

// Scan bucket histogram -> bbase[NBUCK+1]; init bcursor
__global__ __launch_bounds__(256) void k_bscan(const int* __restrict__ bhist,
                                               int* __restrict__ bbase,
                                               int* __restrict__ bcursor) {
    __shared__ int s[NBUCK];
    const int tid = threadIdx.x;
    int v = bhist[tid];
    s[tid] = v;
    __syncthreads();
    for (int off = 1; off < NBUCK; off <<= 1) {
        int t = (tid >= off) ? s[tid - off] : 0;
        __syncthreads();
        s[tid] += t;
        __syncthreads();
    }
    int excl = s[tid] - v;
    bbase[tid] = excl;
    bcursor[tid] = excl;
    if (tid == NBUCK - 1) bbase[NBUCK] = N_EDGES_C;
}

// Pass 1: scatter edges into bucket-sorted tmp, all global writes coalesced.
// Record: (src << 9) | (dst - bucket*BSZ)   [17+9 = 26 bits]
__global__ __launch_bounds__(256) void k_scatter1(
    const int* __restrict__ src, const int* __restrict__ dst,
    int* __restrict__ bcursor, unsigned* __restrict__ tmp) {
    __shared__ int h[NBUCK], sc[NBUCK], gb[NBUCK], lc[NBUCK];
    __shared__ unsigned lbuf[CHUNK];
    const int tid = threadIdx.x;
    const int base = blockIdx.x * CHUNK;
    h[tid] = 0; lc[tid] = 0;
    __syncthreads();
    unsigned rec[EPT]; int bk[EPT];
#pragma unroll
    for (int i = 0; i < EPT; ++i) {
        int e = base + i * 256 + tid;
        if (e < N_EDGES_C) {
            int d = dst[e];
            int b = d / BSZ;
            rec[i] = ((unsigned)src[e] << 9) | (unsigned)(d - b * BSZ);
            bk[i] = b;
            atomicAdd(&h[b], 1);
        } else bk[i] = -1;
    }
    __syncthreads();
    // exclusive scan of per-chunk histogram
    int v = h[tid];
    sc[tid] = v;
    __syncthreads();
    for (int off = 1; off < NBUCK; off <<= 1) {
        int t = (tid >= off) ? sc[tid - off] : 0;
        __syncthreads();
        sc[tid] += t;
        __syncthreads();
    }
    int excl = sc[tid] - v;
    gb[tid] = v ? atomicAdd(&bcursor[tid], v) : 0;  // reserve global span
    sc[tid] = excl;
    __syncthreads();
    // scatter records into LDS (bucket-grouped)
#pragma unroll
    for (int i = 0; i < EPT; ++i) {
        if (bk[i] >= 0) {
            int p = atomicAdd(&lc[bk[i]], 1);
            lbuf[sc[bk[i]] + p] = rec[i];
        }
    }
    __syncthreads();
    // coalesced copy-out per bucket
    const int wid = tid >> 6, lane = tid & 63;
    for (int b = wid; b < NBUCK; b += 4) {
        int n = h[b], g = gb[b], l = sc[b];
        for (int i = lane; i < n; i += 64) tmp[g + i] = lbuf[l + i];
    }
}

// Pass 2: per-bucket local counting sort (LDS) -> offsets + es, coalesced out.
__global__ __launch_bounds__(256) void k_sort2(
    const unsigned* __restrict__ tmp, const int* __restrict__ bbase,
    int* __restrict__ offsets, int* __restrict__ es) {
    __shared__ int h[512], s2[512], cur[512];
    __shared__ int lbuf[BCAP];
    const int b = blockIdx.x, tid = threadIdx.x;
    const int base = bbase[b];
    const int cnt = bbase[b + 1] - base;
    h[tid] = 0; h[tid + 256] = 0;
    __syncthreads();
    for (int i = tid; i < cnt; i += 256) atomicAdd(&h[tmp[base + i] & 511], 1);
    __syncthreads();
    int v0 = h[tid], v1 = h[tid + 256];
    s2[tid] = v0; s2[tid + 256] = v1;
    __syncthreads();
    for (int off = 1; off < 512; off <<= 1) {
        int t0 = (tid >= off) ? s2[tid - off] : 0;
        int t1 = (tid + 256 >= off) ? s2[tid + 256 - off] : 0;
        __syncthreads();
        s2[tid] += t0; s2[tid + 256] += t1;
        __syncthreads();
    }
    int e0 = s2[tid] - v0, e1 = s2[tid + 256] - v1;
    cur[tid] = e0; cur[tid + 256] = e1;
    {   // node offsets (global ids)
        int gn0 = b * BSZ + tid;
        if (tid < BSZ && gn0 < N_NODES_C) offsets[gn0] = base + e0;
        int n1 = tid + 256;
        int gn1 = b * BSZ + n1;
        if (n1 < BSZ && gn1 < N_NODES_C) offsets[gn1] = base + e1;
    }
    __syncthreads();
    for (int i = tid; i < cnt; i += 256) {
        unsigned r = tmp[base + i];
        int ld = r & 511;
        int p = atomicAdd(&cur[ld], 1);
        lbuf[p] = (int)(r >> 9);
    }
    __syncthreads();
    for (int i = tid; i < cnt; i += 256) es[base + i] = lbuf[i];
    if (b == NBUCK - 1 && tid == 0) offsets[N_NODES_C] = N_EDGES_C;
}

// ==================== layers ====================

// Gather-sum: one 32-lane group per node. No LDS, no barriers -> max TLP.
__global__ __launch_bounds__(256) void k_gather(
    const _Float16* __restrict__ h_in, _Float16* __restrict__ agg,
    const int* __restrict__ offsets, const int* __restrict__ es) {
    const int node = (blockIdx.x << 3) + (threadIdx.x >> 5);  // 8 groups/block
    const int lane = threadIdx.x & 31;
    const int c4 = lane * 4;
    const int beg = offsets[node];
    const int end = offsets[node + 1];
    f4 a0 = {0.f, 0.f, 0.f, 0.f}, a1 = a0, a2 = a0, a3 = a0;
    f4 a4 = a0, a5 = a0, a6 = a0, a7 = a0;
    int e = beg;
    for (; e + 8 <= end; e += 8) {
        int s0 = es[e],     s1 = es[e + 1], s2 = es[e + 2], s3 = es[e + 3];
        int s4 = es[e + 4], s5 = es[e + 5], s6 = es[e + 6], s7 = es[e + 7];
        h4 v0 = *(const h4*)(h_in + (size_t)s0 * HID + c4);
        h4 v1 = *(const h4*)(h_in + (size_t)s1 * HID + c4);
        h4 v2 = *(const h4*)(h_in + (size_t)s2 * HID + c4);
        h4 v3 = *(const h4*)(h_in + (size_t)s3 * HID + c4);
        h4 v4 = *(const h4*)(h_in + (size_t)s4 * HID + c4);
        h4 v5 = *(const h4*)(h_in + (size_t)s5 * HID + c4);
        h4 v6 = *(const h4*)(h_in + (size_t)s6 * HID + c4);
        h4 v7 = *(const h4*)(h_in + (size_t)s7 * HID + c4);
        a0 += h2f(v0); a1 += h2f(v1); a2 += h2f(v2); a3 += h2f(v3);
        a4 += h2f(v4); a5 += h2f(v5); a6 += h2f(v6); a7 += h2f(v7);
    }
    for (; e + 4 <= end; e += 4) {
        int s0 = es[e], s1 = es[e + 1], s2 = es[e + 2], s3 = es[e + 3];
        h4 v0 = *(const h4*)(h_in + (size_t)s0 * HID + c4);
        h4 v1 = *(const h4*)(h_in + (size_t)s1 * HID + c4);
        h4 v2 = *(const h4*)(h_in + (size_t)s2 * HID + c4);
        h4 v3 = *(const h4*)(h_in + (size_t)s3 * HID + c4);
        a0 += h2f(v0); a1 += h2f(v1); a2 += h2f(v2); a3 += h2f(v3);
    }
    for (; e < end; ++e)
        a0 += h2f(*(const h4*)(h_in + (size_t)es[e] * HID + c4));
    f4 t = ((a0 + a1) + (a2 + a3)) + ((a4 + a5) + (a6 + a7));
    *(h4*)(agg + (size_t)node * HID + c4) = f2h(t);
}

// MFMA GEMM: h_out = atan(agg @ W_rel + b_rel + h_in @ W_root), fp16 operands.
__global__ __launch_bounds__(256) void k_gemm_mfma(
    const _Float16* __restrict__ agg, const _Float16* __restrict__ h_in,
    _Float16* __restrict__ h_out,
    const _Float16* __restrict__ wT,   // [2][HID][HID] (j,k) for this layer
    const float* __restrict__ b_rel) {
    const int wave = (blockIdx.x << 2) + (threadIdx.x >> 6);
    const int lane = threadIdx.x & 63;
    const int ntile = wave >> 3;
    const int jt = wave & 7;
    const int row = lane & 15;
    const int kg = lane >> 4;
    const int node0 = ntile << 4;
    const int j0 = jt << 4;

    const _Float16* aP  = agg  + (size_t)(node0 + row) * HID + (kg << 3);
    const _Float16* hP  = h_in + (size_t)(node0 + row) * HID + (kg << 3);
    const _Float16* wrP = wT + (size_t)(j0 + row) * HID + (kg << 3);
    const _Float16* woP = wT + (size_t)(HID + j0 + row) * HID + (kg << 3);

    f32x4 acc = {0.f, 0.f, 0.f, 0.f};
#pragma unroll
    for (int ks = 0; ks < 4; ++ks) {
        const int ko = ks * 32;
        f16x8 aA = *(const f16x8*)(aP + ko);
        f16x8 aH = *(const f16x8*)(hP + ko);
        f16x8 bR = *(const f16x8*)(wrP + ko);
        f16x8 bO = *(const f16x8*)(woP + ko);
        acc = __builtin_amdgcn_mfma_f32_16x16x32_f16(aA, bR, acc, 0, 0, 0);
        acc = __builtin_amdgcn_mfma_f32_16x16x32_f16(aH, bO, acc, 0, 0, 0);
    }
    const int j = j0 + row;
    const float b = b_rel[j];
#pragma unroll
    for (int r = 0; r < 4; ++r) {
        float v = atanf(acc[r] + b);
        h_out[(size_t)(node0 + (kg << 2) + r) * HID + j] = (_Float16)v;
    }
}

// Pool stage 1: per (graph, segment) partial sums over fp16 h -> fp32 part
__global__ __launch_bounds__(256) void k_pool1(
    const _Float16* __restrict__ h, const int* __restrict__ batch,
    float* __restrict__ part) {
    __shared__ float sm[2][HID];
    const int b = blockIdx.x;
    const int g = b >> 3, s = b & (SEG - 1);
    const int j = threadIdx.x & 127;
    const int half = threadIdx.x >> 7;

    int lo = 0, hi = N_NODES_C;
    while (lo < hi) { int mid = (lo + hi) >> 1; if (batch[mid] < g) lo = mid + 1; else hi = mid; }
    int start = lo;
    hi = N_NODES_C;
    while (lo < hi) { int mid = (lo + hi) >> 1; if (batch[mid] < g + 1) lo = mid + 1; else hi = mid; }
    int end = lo;
    int len = end - start;
    int s0 = start + (int)((long long)len * s / SEG);
    int s1 = start + (int)((long long)len * (s + 1) / SEG);

    float acc = 0.f;
    for (int i = s0 + half; i < s1; i += 2) acc += (float)h[(size_t)i * HID + j];
    sm[half][j] = acc;
    __syncthreads();
    if (threadIdx.x < HID) part[(size_t)b * HID + j] = sm[0][j] + sm[1][j];
}

// Pool stage 2 + head
__global__ __launch_bounds__(128) void k_head(
    const float* __restrict__ part, const float* __restrict__ W_out,
    const float* __restrict__ b_out, float* __restrict__ out) {
    __shared__ float sf[HID];
    const int g = blockIdx.x;
    const int j = threadIdx.x;
    float v = 0.f;
    for (int s = 0; s < SEG; ++s) v += part[(size_t)(g * SEG + s) * HID + j];
    sf[j] = v;
    __syncthreads();
    if (j < OUTD) {
        float a = b_out[j];
        for (int k = 0; k < HID; ++k) a += sf[k] * W_out[k * OUTD + j];
        out[g * OUTD + j] = 1.f / (1.f + expf(-a));
    }
}

extern "C" void kernel_launch(void* const* d_in, const int* in_sizes, int n_in,
                              void* d_out, int out_size, void* d_ws, size_t ws_size,
                              hipStream_t stream) {
    const float* x      = (const float*)d_in[0];
    const int*   ei     = (const int*)d_in[1];
    const int*   src    = ei;
    const int*   dst    = ei + N_EDGES_C;
    const int*   batch  = (const int*)d_in[2];
    const float* W_rel  = (const float*)d_in[3];
    const float* b_rel  = (const float*)d_in[4];
    const float* W_root = (const float*)d_in[5];
    const float* W_out  = (const float*)d_in[6];
    const float* b_out  = (const float*)d_in[7];
    float* out = (float*)d_out;

    char* ws = (char*)d_ws;
    size_t off = 0;
    auto alloc = [&](size_t bytes) { void* p = ws + off; off = align_up(off + bytes, 256); return p; };
    _Float16* xh    = (_Float16*)alloc((size_t)N_NODES_C * HID * 2);  // x fp16; reused as h2
    _Float16* h1h   = (_Float16*)alloc((size_t)N_NODES_C * HID * 2);  // h1 fp16; reused as h3
    _Float16* agg16 = (_Float16*)alloc((size_t)N_NODES_C * HID * 2);
    _Float16* wT    = (_Float16*)alloc((size_t)3 * 2 * HID * HID * 2);
    int*   offsets = (int*)alloc((size_t)(N_NODES_C + 1) * sizeof(int));
    int*   es      = (int*)alloc((size_t)N_EDGES_C * sizeof(int));
    unsigned* tmp  = (unsigned*)alloc((size_t)N_EDGES_C * sizeof(unsigned));
    int*   bhist   = (int*)alloc(NBUCK * sizeof(int));
    int*   bbase   = (int*)alloc((NBUCK + 1) * sizeof(int));
    int*   bcursor = (int*)alloc(NBUCK * sizeof(int));
    float* part    = (float*)alloc((size_t)N_GRAPHS_C * SEG * HID * sizeof(float));

    const int gather_blocks = N_NODES_C / 8;           // 12500
    const int mfma_blocks = (N_NODES_C / 16) * 8 / 4;  // 12500
    const int scat_blocks = (N_EDGES_C + CHUNK - 1) / CHUNK;  // 782
    const size_t WTL = (size_t)2 * HID * HID;

    // ---- weight prep + x -> fp16 ----
    k_wprep<<<768, 128, 0, stream>>>(W_rel, W_root, wT);
    k_cvt<<<(N_NODES_C * HID) / 4 / 256, 256, 0, stream>>>(x, xh);

    // ---- CSR build: bucket sort, all global scatter staged through LDS ----
    k_zeroB<<<1, 256, 0, stream>>>(bhist);
    k_hist1<<<1024, 256, 0, stream>>>(dst, bhist);
    k_bscan<<<1, 256, 0, stream>>>(bhist, bbase, bcursor);
    k_scatter1<<<scat_blocks, 256, 0, stream>>>(src, dst, bcursor, tmp);
    k_sort2<<<NBUCK, 256, 0, stream>>>(tmp, bbase, offsets, es);

    // ---- 3 GraphConv layers: gather (latency-opt) + MFMA gemm ----
    k_gather<<<gather_blocks, 256, 0, stream>>>(xh, agg16, offsets, es);
    k_gemm_mfma<<<mfma_blocks, 256, 0, stream>>>(agg16, xh, h1h, wT + 0 * WTL, b_rel + 0 * HID);
    k_gather<<<gather_blocks, 256, 0, stream>>>(h1h, agg16, offsets, es);
    k_gemm_mfma<<<mfma_blocks, 256, 0, stream>>>(agg16, h1h, xh, wT + 1 * WTL, b_rel + 1 * HID);
    k_gather<<<gather_blocks, 256, 0, stream>>>(xh, agg16, offsets, es);
    k_gemm_mfma<<<mfma_blocks, 256, 0, stream>>>(agg16, xh, h1h, wT + 2 * WTL, b_rel + 2 * HID);

    // ---- pool + head ----
    k_pool1<<<N_GRAPHS_C * SEG, 256, 0, stream>>>(h1h, batch, part);
    k_head<<<N_GRAPHS_C, 128, 0, stream>>>(part, W_out, b_out, out);
}

// Round 14
// 478.376 us; speedup vs baseline: 2.1143x; 1.1920x over previous
//
#include <hip/hip_runtime.h>
#include <hip/hip_bf16.h>

#define N_NODES_C 100000
#define N_EDGES_C 1600000
#define HID 128
#define OUTD 8
#define N_GRAPHS_C 128
#define SEG 8     // pool segments per graph
#define NBUCK 256 // CSR sort buckets
#define BSZ 391   // nodes per bucket (256*391 = 100096 >= 100000)
#define BCAP 8192 // LDS capacity per bucket in k_sort2
#define CHUNK 2048
#define EPT 8     // edges per thread in k_scatter1
#define NTILES (N_NODES_C / 16)              // 6250
#define NTPW 8                               // node-tiles per wave in gemm
#define NGRP ((NTILES + NTPW - 1) / NTPW)    // 782

typedef __attribute__((ext_vector_type(4))) float f4;
typedef __attribute__((ext_vector_type(4))) _Float16 h4;
typedef __attribute__((ext_vector_type(8))) _Float16 f16x8;
typedef __attribute__((ext_vector_type(4))) float f32x4;

static inline size_t align_up(size_t x, size_t a) { return (x + a - 1) & ~(a - 1); }

__device__ __forceinline__ f4 h2f(h4 v) { return __builtin_convertvector(v, f4); }
__device__ __forceinline__ h4 f2h(f4 v) { return __builtin_convertvector(v, h4); }

__global__ __launch_bounds__(256) void k_cvt(const float* __restrict__ in,
                                             _Float16* __restrict__ out) {
    int i = blockIdx.x * blockDim.x + threadIdx.x;
    f4 v = *(const f4*)(in + (size_t)i * 4);
    *(h4*)(out + (size_t)i * 4) = f2h(v);
}

// Build wT fp16 [L][2][j][k] from W_rel/W_root fp32 [L][k][j]
__global__ __launch_bounds__(128) void k_wprep(
    const float* __restrict__ W_rel, const float* __restrict__ W_root,
    _Float16* __restrict__ wT) {
    const int b = blockIdx.x;
    const int l = b >> 8;
    const int m = (b >> 7) & 1;
    const int j = b & 127;
    const int k = threadIdx.x;
    const float* W = (m == 0 ? W_rel : W_root) + (size_t)l * HID * HID;
    wT[(((size_t)l * 2 + m) * HID + j) * HID + k] = (_Float16)W[k * HID + j];
}

// ==================== CSR build: 2-pass LDS-staged bucket sort ====================

__global__ __launch_bounds__(256) void k_zeroB(int* __restrict__ b) { b[threadIdx.x] = 0; }

__global__ __launch_bounds__(256) void k_hist1(const int* __restrict__ dst,
                                               int* __restrict__ bhist) {
    __shared__ int h[NBUCK];
    h[threadIdx.x] = 0;
    __syncthreads();
    int stride = gridDim.x * blockDim.x;
    for (int e = blockIdx.x * 256 + threadIdx.x; e < N_EDGES_C; e += stride)
        atomicAdd(&h[dst[e] / BSZ], 1);
    __syncthreads();
    if (h[threadIdx.x]) atomicAdd(&bhist[threadIdx.x], h[threadIdx.x]);
}

__global__ __launch_bounds__(256) void k_bscan(const int* __restrict__ bhist,
                                               int* __restrict__ bbase,
                                               int* __restrict__ bcursor) {
    __shared__ int s[NBUCK];
    const int tid = threadIdx.x;
    int v = bhist[tid];
    s[tid] = v;
    __syncthreads();
    for (int off = 1; off < NBUCK; off <<= 1) {
        int t = (tid >= off) ? s[tid - off] : 0;
        __syncthreads();
        s[tid] += t;
        __syncthreads();
    }
    int excl = s[tid] - v;
    bbase[tid] = excl;
    bcursor[tid] = excl;
    if (tid == NBUCK - 1) bbase[NBUCK] = N_EDGES_C;
}

__global__ __launch_bounds__(256) void k_scatter1(
    const int* __restrict__ src, const int* __restrict__ dst,
    int* __restrict__ bcursor, unsigned* __restrict__ tmp) {
    __shared__ int h[NBUCK], sc[NBUCK], gb[NBUCK], lc[NBUCK];
    __shared__ unsigned lbuf[CHUNK];
    const int tid = threadIdx.x;
    const int base = blockIdx.x * CHUNK;
    h[tid] = 0; lc[tid] = 0;
    __syncthreads();
    unsigned rec[EPT]; int bk[EPT];
#pragma unroll
    for (int i = 0; i < EPT; ++i) {
        int e = base + i * 256 + tid;
        if (e < N_EDGES_C) {
            int d = dst[e];
            int b = d / BSZ;
            rec[i] = ((unsigned)src[e] << 9) | (unsigned)(d - b * BSZ);
            bk[i] = b;
            atomicAdd(&h[b], 1);
        } else bk[i] = -1;
    }
    __syncthreads();
    int v = h[tid];
    sc[tid] = v;
    __syncthreads();
    for (int off = 1; off < NBUCK; off <<= 1) {
        int t = (tid >= off) ? sc[tid - off] : 0;
        __syncthreads();
        sc[tid] += t;
        __syncthreads();
    }
    int excl = sc[tid] - v;
    gb[tid] = v ? atomicAdd(&bcursor[tid], v) : 0;
    sc[tid] = excl;
    __syncthreads();
#pragma unroll
    for (int i = 0; i < EPT; ++i) {
        if (bk[i] >= 0) {
            int p = atomicAdd(&lc[bk[i]], 1);
            lbuf[sc[bk[i]] + p] = rec[i];
        }
    }
    __syncthreads();
    const int wid = tid >> 6, lane = tid & 63;
    for (int b = wid; b < NBUCK; b += 4) {
        int n = h[b], g = gb[b], l = sc[b];
        for (int i = lane; i < n; i += 64) tmp[g + i] = lbuf[l + i];
    }
}

__global__ __launch_bounds__(256) void k_sort2(
    const unsigned* __restrict__ tmp, const int* __restrict__ bbase,
    int* __restrict__ offsets, int* __restrict__ es) {
    __shared__ int h[512], s2[512], cur[512];
    __shared__ int lbuf[BCAP];
    const int b = blockIdx.x, tid = threadIdx.x;
    const int base = bbase[b];
    const int cnt = bbase[b + 1] - base;
    h[tid] = 0; h[tid + 256] = 0;
    __syncthreads();
    for (int i = tid; i < cnt; i += 256) atomicAdd(&h[tmp[base + i] & 511], 1);
    __syncthreads();
    int v0 = h[tid], v1 = h[tid + 256];
    s2[tid] = v0; s2[tid + 256] = v1;
    __syncthreads();
    for (int off = 1; off < 512; off <<= 1) {
        int t0 = (tid >= off) ? s2[tid - off] : 0;
        int t1 = (tid + 256 >= off) ? s2[tid + 256 - off] : 0;
        __syncthreads();
        s2[tid] += t0; s2[tid + 256] += t1;
        __syncthreads();
    }
    int e0 = s2[tid] - v0, e1 = s2[tid + 256] - v1;
    cur[tid] = e0; cur[tid + 256] = e1;
    {
        int gn0 = b * BSZ + tid;
        if (tid < BSZ && gn0 < N_NODES_C) offsets[gn0] = base + e0;
        int n1 = tid + 256;
        int gn1 = b * BSZ + n1;
        if (n1 < BSZ && gn1 < N_NODES_C) offsets[gn1] = base + e1;
    }
    __syncthreads();
    for (int i = tid; i < cnt; i += 256) {
        unsigned r = tmp[base + i];
        int ld = r & 511;
        int p = atomicAdd(&cur[ld], 1);
        lbuf[p] = (int)(r >> 9);
    }
    __syncthreads();
    for (int i = tid; i < cnt; i += 256) es[base + i] = lbuf[i];
    if (b == NBUCK - 1 && tid == 0) offsets[N_NODES_C] = N_EDGES_C;
}

// ==================== layers ====================

// Gather-sum: one 32-lane group per node. No LDS, no barriers -> max TLP.
__global__ __launch_bounds__(256) void k_gather(
    const _Float16* __restrict__ h_in, _Float16* __restrict__ agg,
    const int* __restrict__ offsets, const int* __restrict__ es) {
    const int node = (blockIdx.x << 3) + (threadIdx.x >> 5);
    const int lane = threadIdx.x & 31;
    const int c4 = lane * 4;
    const int beg = offsets[node];
    const int end = offsets[node + 1];
    f4 a0 = {0.f, 0.f, 0.f, 0.f}, a1 = a0, a2 = a0, a3 = a0;
    f4 a4 = a0, a5 = a0, a6 = a0, a7 = a0;
    int e = beg;
    for (; e + 8 <= end; e += 8) {
        int s0 = es[e],     s1 = es[e + 1], s2 = es[e + 2], s3 = es[e + 3];
        int s4 = es[e + 4], s5 = es[e + 5], s6 = es[e + 6], s7 = es[e + 7];
        h4 v0 = *(const h4*)(h_in + (size_t)s0 * HID + c4);
        h4 v1 = *(const h4*)(h_in + (size_t)s1 * HID + c4);
        h4 v2 = *(const h4*)(h_in + (size_t)s2 * HID + c4);
        h4 v3 = *(const h4*)(h_in + (size_t)s3 * HID + c4);
        h4 v4 = *(const h4*)(h_in + (size_t)s4 * HID + c4);
        h4 v5 = *(const h4*)(h_in + (size_t)s5 * HID + c4);
        h4 v6 = *(const h4*)(h_in + (size_t)s6 * HID + c4);
        h4 v7 = *(const h4*)(h_in + (size_t)s7 * HID + c4);
        a0 += h2f(v0); a1 += h2f(v1); a2 += h2f(v2); a3 += h2f(v3);
        a4 += h2f(v4); a5 += h2f(v5); a6 += h2f(v6); a7 += h2f(v7);
    }
    for (; e + 4 <= end; e += 4) {
        int s0 = es[e], s1 = es[e + 1], s2 = es[e + 2], s3 = es[e + 3];
        h4 v0 = *(const h4*)(h_in + (size_t)s0 * HID + c4);
        h4 v1 = *(const h4*)(h_in + (size_t)s1 * HID + c4);
        h4 v2 = *(const h4*)(h_in + (size_t)s2 * HID + c4);
        h4 v3 = *(const h4*)(h_in + (size_t)s3 * HID + c4);
        a0 += h2f(v0); a1 += h2f(v1); a2 += h2f(v2); a3 += h2f(v3);
    }
    for (; e < end; ++e)
        a0 += h2f(*(const h4*)(h_in + (size_t)es[e] * HID + c4));
    f4 t = ((a0 + a1) + (a2 + a3)) + ((a4 + a5) + (a6 + a7));
    *(h4*)(agg + (size_t)node * HID + c4) = f2h(t);
}

// MFMA GEMM, W-in-registers: wave owns a 16-j tile, loops 8 node-tiles.
// W loaded ONCE per wave (32 VGPR), A/H streamed. 6256 waves total (all resident).
__global__ __launch_bounds__(256) void k_gemm_mfma(
    const _Float16* __restrict__ agg, const _Float16* __restrict__ h_in,
    _Float16* __restrict__ h_out,
    const _Float16* __restrict__ wT,   // [2][HID][HID] (j,k) for this layer
    const float* __restrict__ b_rel) {
    const int wave = (blockIdx.x << 2) + (threadIdx.x >> 6);  // 0..6255
    const int lane = threadIdx.x & 63;
    const int g = wave >> 3;       // ntile group 0..781
    const int jt = wave & 7;
    const int row = lane & 15;
    const int kg = lane >> 4;      // 0..3
    const int j0 = jt << 4;
    const int j = j0 + row;
    const float b = b_rel[j];

    const _Float16* wrP = wT + (size_t)(j0 + row) * HID + (kg << 3);
    const _Float16* woP = wT + (size_t)(HID + j0 + row) * HID + (kg << 3);
    const f16x8 bR0 = *(const f16x8*)(wrP + 0);
    const f16x8 bR1 = *(const f16x8*)(wrP + 32);
    const f16x8 bR2 = *(const f16x8*)(wrP + 64);
    const f16x8 bR3 = *(const f16x8*)(wrP + 96);
    const f16x8 bO0 = *(const f16x8*)(woP + 0);
    const f16x8 bO1 = *(const f16x8*)(woP + 32);
    const f16x8 bO2 = *(const f16x8*)(woP + 64);
    const f16x8 bO3 = *(const f16x8*)(woP + 96);

    const int ntBeg = g * NTPW;
    const int ntEnd = (ntBeg + NTPW < NTILES) ? ntBeg + NTPW : NTILES;
    for (int nt = ntBeg; nt < ntEnd; ++nt) {
        const int node0 = nt << 4;
        const _Float16* aP = agg  + (size_t)(node0 + row) * HID + (kg << 3);
        const _Float16* hP = h_in + (size_t)(node0 + row) * HID + (kg << 3);
        f32x4 acc = {0.f, 0.f, 0.f, 0.f};
        acc = __builtin_amdgcn_mfma_f32_16x16x32_f16(*(const f16x8*)(aP + 0),  bR0, acc, 0, 0, 0);
        acc = __builtin_amdgcn_mfma_f32_16x16x32_f16(*(const f16x8*)(hP + 0),  bO0, acc, 0, 0, 0);
        acc = __builtin_amdgcn_mfma_f32_16x16x32_f16(*(const f16x8*)(aP + 32), bR1, acc, 0, 0, 0);
        acc = __builtin_amdgcn_mfma_f32_16x16x32_f16(*(const f16x8*)(hP + 32), bO1, acc, 0, 0, 0);
        acc = __builtin_amdgcn_mfma_f32_16x16x32_f16(*(const f16x8*)(aP + 64), bR2, acc, 0, 0, 0);
        acc = __builtin_amdgcn_mfma_f32_16x16x32_f16(*(const f16x8*)(hP + 64), bO2, acc, 0, 0, 0);
        acc = __builtin_amdgcn_mfma_f32_16x16x32_f16(*(const f16x8*)(aP + 96), bR3, acc, 0, 0, 0);
        acc = __builtin_amdgcn_mfma_f32_16x16x32_f16(*(const f16x8*)(hP + 96), bO3, acc, 0, 0, 0);
#pragma unroll
        for (int r = 0; r < 4; ++r) {
            float v = atanf(acc[r] + b);
            h_out[(size_t)(node0 + (kg << 2) + r) * HID + j] = (_Float16)v;
        }
    }
}

// Pool stage 1: per (graph, segment) partial sums over fp16 h -> fp32 part
__global__ __launch_bounds__(256) void k_pool1(
    const _Float16* __restrict__ h, const int* __restrict__ batch,
    float* __restrict__ part) {
    __shared__ float sm[2][HID];
    const int b = blockIdx.x;
    const int g = b >> 3, s = b & (SEG - 1);
    const int j = threadIdx.x & 127;
    const int half = threadIdx.x >> 7;

    int lo = 0, hi = N_NODES_C;
    while (lo < hi) { int mid = (lo + hi) >> 1; if (batch[mid] < g) lo = mid + 1; else hi = mid; }
    int start = lo;
    hi = N_NODES_C;
    while (lo < hi) { int mid = (lo + hi) >> 1; if (batch[mid] < g + 1) lo = mid + 1; else hi = mid; }
    int end = lo;
    int len = end - start;
    int s0 = start + (int)((long long)len * s / SEG);
    int s1 = start + (int)((long long)len * (s + 1) / SEG);

    float acc = 0.f;
    for (int i = s0 + half; i < s1; i += 2) acc += (float)h[(size_t)i * HID + j];
    sm[half][j] = acc;
    __syncthreads();
    if (threadIdx.x < HID) part[(size_t)b * HID + j] = sm[0][j] + sm[1][j];
}

// Pool stage 2 + head
__global__ __launch_bounds__(128) void k_head(
    const float* __restrict__ part, const float* __restrict__ W_out,
    const float* __restrict__ b_out, float* __restrict__ out) {
    __shared__ float sf[HID];
    const int g = blockIdx.x;
    const int j = threadIdx.x;
    float v = 0.f;
    for (int s = 0; s < SEG; ++s) v += part[(size_t)(g * SEG + s) * HID + j];
    sf[j] = v;
    __syncthreads();
    if (j < OUTD) {
        float a = b_out[j];
        for (int k = 0; k < HID; ++k) a += sf[k] * W_out[k * OUTD + j];
        out[g * OUTD + j] = 1.f / (1.f + expf(-a));
    }
}

extern "C" void kernel_launch(void* const* d_in, const int* in_sizes, int n_in,
                              void* d_out, int out_size, void* d_ws, size_t ws_size,
                              hipStream_t stream) {
    const float* x      = (const float*)d_in[0];
    const int*   ei     = (const int*)d_in[1];
    const int*   src    = ei;
    const int*   dst    = ei + N_EDGES_C;
    const int*   batch  = (const int*)d_in[2];
    const float* W_rel  = (const float*)d_in[3];
    const float* b_rel  = (const float*)d_in[4];
    const float* W_root = (const float*)d_in[5];
    const float* W_out  = (const float*)d_in[6];
    const float* b_out  = (const float*)d_in[7];
    float* out = (float*)d_out;

    char* ws = (char*)d_ws;
    size_t off = 0;
    auto alloc = [&](size_t bytes) { void* p = ws + off; off = align_up(off + bytes, 256); return p; };
    _Float16* xh    = (_Float16*)alloc((size_t)N_NODES_C * HID * 2);
    _Float16* h1h   = (_Float16*)alloc((size_t)N_NODES_C * HID * 2);
    _Float16* agg16 = (_Float16*)alloc((size_t)N_NODES_C * HID * 2);
    _Float16* wT    = (_Float16*)alloc((size_t)3 * 2 * HID * HID * 2);
    int*   offsets = (int*)alloc((size_t)(N_NODES_C + 1) * sizeof(int));
    int*   es      = (int*)alloc((size_t)N_EDGES_C * sizeof(int));
    unsigned* tmp  = (unsigned*)alloc((size_t)N_EDGES_C * sizeof(unsigned));
    int*   bhist   = (int*)alloc(NBUCK * sizeof(int));
    int*   bbase   = (int*)alloc((NBUCK + 1) * sizeof(int));
    int*   bcursor = (int*)alloc(NBUCK * sizeof(int));
    float* part    = (float*)alloc((size_t)N_GRAPHS_C * SEG * HID * sizeof(float));

    const int gather_blocks = N_NODES_C / 8;          // 12500
    const int mfma_blocks = NGRP * 8 / 4;             // 782*8 waves / 4 = 1564
    const int scat_blocks = (N_EDGES_C + CHUNK - 1) / CHUNK;
    const size_t WTL = (size_t)2 * HID * HID;

    // ---- weight prep + x -> fp16 ----
    k_wprep<<<768, 128, 0, stream>>>(W_rel, W_root, wT);
    k_cvt<<<(N_NODES_C * HID) / 4 / 256, 256, 0, stream>>>(x, xh);

    // ---- CSR build: bucket sort, all global scatter staged through LDS ----
    k_zeroB<<<1, 256, 0, stream>>>(bhist);
    k_hist1<<<1024, 256, 0, stream>>>(dst, bhist);
    k_bscan<<<1, 256, 0, stream>>>(bhist, bbase, bcursor);
    k_scatter1<<<scat_blocks, 256, 0, stream>>>(src, dst, bcursor, tmp);
    k_sort2<<<NBUCK, 256, 0, stream>>>(tmp, bbase, offsets, es);

    // ---- 3 GraphConv layers: gather (latency-opt) + MFMA gemm (W-in-reg) ----
    k_gather<<<gather_blocks, 256, 0, stream>>>(xh, agg16, offsets, es);
    k_gemm_mfma<<<mfma_blocks, 256, 0, stream>>>(agg16, xh, h1h, wT + 0 * WTL, b_rel + 0 * HID);
    k_gather<<<gather_blocks, 256, 0, stream>>>(h1h, agg16, offsets, es);
    k_gemm_mfma<<<mfma_blocks, 256, 0, stream>>>(agg16, h1h, xh, wT + 1 * WTL, b_rel + 1 * HID);
    k_gather<<<gather_blocks, 256, 0, stream>>>(xh, agg16, offsets, es);
    k_gemm_mfma<<<mfma_blocks, 256, 0, stream>>>(agg16, xh, h1h, wT + 2 * WTL, b_rel + 2 * HID);

    // ---- pool + head ----
    k_pool1<<<N_GRAPHS_C * SEG, 256, 0, stream>>>(h1h, batch, part);
    k_head<<<N_GRAPHS_C, 128, 0, stream>>>(part, W_out, b_out, out);
}

// Round 15
// 477.606 us; speedup vs baseline: 2.1177x; 1.0016x over previous
//
#include <hip/hip_runtime.h>
#include <hip/hip_bf16.h>

#define N_NODES_C 100000
#define N_EDGES_C 1600000
#define HID 128
#define OUTD 8
#define N_GRAPHS_C 128
#define SEG 8     // pool segments per graph
#define NBUCK 256 // CSR sort buckets
#define BSZ 391   // nodes per bucket (256*391 = 100096 >= 100000)
#define BCAP 8192 // LDS capacity per bucket in k_sort2
#define CHUNK 2048
#define EPT 8     // edges per thread in k_scatter1
#define NTILES (N_NODES_C / 16)              // 6250
#define NTPW 8                               // node-tiles per wave in gemm
#define NGRP ((NTILES + NTPW - 1) / NTPW)    // 782

typedef __attribute__((ext_vector_type(4))) float f4;
typedef __attribute__((ext_vector_type(4))) _Float16 h4;
typedef __attribute__((ext_vector_type(8))) _Float16 f16x8;
typedef __attribute__((ext_vector_type(4))) float f32x4;

static inline size_t align_up(size_t x, size_t a) { return (x + a - 1) & ~(a - 1); }

__device__ __forceinline__ f4 h2f(h4 v) { return __builtin_convertvector(v, f4); }
__device__ __forceinline__ h4 f2h(f4 v) { return __builtin_convertvector(v, h4); }

__global__ __launch_bounds__(256) void k_cvt(const float* __restrict__ in,
                                             _Float16* __restrict__ out) {
    int i = blockIdx.x * blockDim.x + threadIdx.x;
    f4 v = *(const f4*)(in + (size_t)i * 4);
    *(h4*)(out + (size_t)i * 4) = f2h(v);
}

// Build wT fp16 [L][2][j][k] from W_rel/W_root fp32 [L][k][j]
__global__ __launch_bounds__(128) void k_wprep(
    const float* __restrict__ W_rel, const float* __restrict__ W_root,
    _Float16* __restrict__ wT) {
    const int b = blockIdx.x;
    const int l = b >> 8;
    const int m = (b >> 7) & 1;
    const int j = b & 127;
    const int k = threadIdx.x;
    const float* W = (m == 0 ? W_rel : W_root) + (size_t)l * HID * HID;
    wT[(((size_t)l * 2 + m) * HID + j) * HID + k] = (_Float16)W[k * HID + j];
}

// ==================== CSR build: 2-pass LDS-staged bucket sort ====================

__global__ __launch_bounds__(256) void k_zeroB(int* __restrict__ b) { b[threadIdx.x] = 0; }

__global__ __launch_bounds__(256) void k_hist1(const int* __restrict__ dst,
                                               int* __restrict__ bhist) {
    __shared__ int h[NBUCK];
    h[threadIdx.x] = 0;
    __syncthreads();
    int stride = gridDim.x * blockDim.x;
    for (int e = blockIdx.x * 256 + threadIdx.x; e < N_EDGES_C; e += stride)
        atomicAdd(&h[dst[e] / BSZ], 1);
    __syncthreads();
    if (h[threadIdx.x]) atomicAdd(&bhist[threadIdx.x], h[threadIdx.x]);
}

__global__ __launch_bounds__(256) void k_bscan(const int* __restrict__ bhist,
                                               int* __restrict__ bbase,
                                               int* __restrict__ bcursor) {
    __shared__ int s[NBUCK];
    const int tid = threadIdx.x;
    int v = bhist[tid];
    s[tid] = v;
    __syncthreads();
    for (int off = 1; off < NBUCK; off <<= 1) {
        int t = (tid >= off) ? s[tid - off] : 0;
        __syncthreads();
        s[tid] += t;
        __syncthreads();
    }
    int excl = s[tid] - v;
    bbase[tid] = excl;
    bcursor[tid] = excl;
    if (tid == NBUCK - 1) bbase[NBUCK] = N_EDGES_C;
}

__global__ __launch_bounds__(256) void k_scatter1(
    const int* __restrict__ src, const int* __restrict__ dst,
    int* __restrict__ bcursor, unsigned* __restrict__ tmp) {
    __shared__ int h[NBUCK], sc[NBUCK], gb[NBUCK], lc[NBUCK];
    __shared__ unsigned lbuf[CHUNK];
    const int tid = threadIdx.x;
    const int base = blockIdx.x * CHUNK;
    h[tid] = 0; lc[tid] = 0;
    __syncthreads();
    unsigned rec[EPT]; int bk[EPT];
#pragma unroll
    for (int i = 0; i < EPT; ++i) {
        int e = base + i * 256 + tid;
        if (e < N_EDGES_C) {
            int d = dst[e];
            int b = d / BSZ;
            rec[i] = ((unsigned)src[e] << 9) | (unsigned)(d - b * BSZ);
            bk[i] = b;
            atomicAdd(&h[b], 1);
        } else bk[i] = -1;
    }
    __syncthreads();
    int v = h[tid];
    sc[tid] = v;
    __syncthreads();
    for (int off = 1; off < NBUCK; off <<= 1) {
        int t = (tid >= off) ? sc[tid - off] : 0;
        __syncthreads();
        sc[tid] += t;
        __syncthreads();
    }
    int excl = sc[tid] - v;
    gb[tid] = v ? atomicAdd(&bcursor[tid], v) : 0;
    sc[tid] = excl;
    __syncthreads();
#pragma unroll
    for (int i = 0; i < EPT; ++i) {
        if (bk[i] >= 0) {
            int p = atomicAdd(&lc[bk[i]], 1);
            lbuf[sc[bk[i]] + p] = rec[i];
        }
    }
    __syncthreads();
    const int wid = tid >> 6, lane = tid & 63;
    for (int b = wid; b < NBUCK; b += 4) {
        int n = h[b], g = gb[b], l = sc[b];
        for (int i = lane; i < n; i += 64) tmp[g + i] = lbuf[l + i];
    }
}

__global__ __launch_bounds__(256) void k_sort2(
    const unsigned* __restrict__ tmp, const int* __restrict__ bbase,
    int* __restrict__ offsets, int* __restrict__ es) {
    __shared__ int h[512], s2[512], cur[512];
    __shared__ int lbuf[BCAP];
    const int b = blockIdx.x, tid = threadIdx.x;
    const int base = bbase[b];
    const int cnt = bbase[b + 1] - base;
    h[tid] = 0; h[tid + 256] = 0;
    __syncthreads();
    for (int i = tid; i < cnt; i += 256) atomicAdd(&h[tmp[base + i] & 511], 1);
    __syncthreads();
    int v0 = h[tid], v1 = h[tid + 256];
    s2[tid] = v0; s2[tid + 256] = v1;
    __syncthreads();
    for (int off = 1; off < 512; off <<= 1) {
        int t0 = (tid >= off) ? s2[tid - off] : 0;
        int t1 = (tid + 256 >= off) ? s2[tid + 256 - off] : 0;
        __syncthreads();
        s2[tid] += t0; s2[tid + 256] += t1;
        __syncthreads();
    }
    int e0 = s2[tid] - v0, e1 = s2[tid + 256] - v1;
    cur[tid] = e0; cur[tid + 256] = e1;
    {
        int gn0 = b * BSZ + tid;
        if (tid < BSZ && gn0 < N_NODES_C) offsets[gn0] = base + e0;
        int n1 = tid + 256;
        int gn1 = b * BSZ + n1;
        if (n1 < BSZ && gn1 < N_NODES_C) offsets[gn1] = base + e1;
    }
    __syncthreads();
    for (int i = tid; i < cnt; i += 256) {
        unsigned r = tmp[base + i];
        int ld = r & 511;
        int p = atomicAdd(&cur[ld], 1);
        lbuf[p] = (int)(r >> 9);
    }
    __syncthreads();
    for (int i = tid; i < cnt; i += 256) es[base + i] = lbuf[i];
    if (b == NBUCK - 1 && tid == 0) offsets[N_NODES_C] = N_EDGES_C;
}

// ==================== layers ====================

// Gather-sum: one 32-lane group per node. No LDS, no barriers -> max TLP.
__global__ __launch_bounds__(256) void k_gather(
    const _Float16* __restrict__ h_in, _Float16* __restrict__ agg,
    const int* __restrict__ offsets, const int* __restrict__ es) {
    const int node = (blockIdx.x << 3) + (threadIdx.x >> 5);
    const int lane = threadIdx.x & 31;
    const int c4 = lane * 4;
    const int beg = offsets[node];
    const int end = offsets[node + 1];
    f4 a0 = {0.f, 0.f, 0.f, 0.f}, a1 = a0, a2 = a0, a3 = a0;
    f4 a4 = a0, a5 = a0, a6 = a0, a7 = a0;
    int e = beg;
    for (; e + 8 <= end; e += 8) {
        int s0 = es[e],     s1 = es[e + 1], s2 = es[e + 2], s3 = es[e + 3];
        int s4 = es[e + 4], s5 = es[e + 5], s6 = es[e + 6], s7 = es[e + 7];
        h4 v0 = *(const h4*)(h_in + (size_t)s0 * HID + c4);
        h4 v1 = *(const h4*)(h_in + (size_t)s1 * HID + c4);
        h4 v2 = *(const h4*)(h_in + (size_t)s2 * HID + c4);
        h4 v3 = *(const h4*)(h_in + (size_t)s3 * HID + c4);
        h4 v4 = *(const h4*)(h_in + (size_t)s4 * HID + c4);
        h4 v5 = *(const h4*)(h_in + (size_t)s5 * HID + c4);
        h4 v6 = *(const h4*)(h_in + (size_t)s6 * HID + c4);
        h4 v7 = *(const h4*)(h_in + (size_t)s7 * HID + c4);
        a0 += h2f(v0); a1 += h2f(v1); a2 += h2f(v2); a3 += h2f(v3);
        a4 += h2f(v4); a5 += h2f(v5); a6 += h2f(v6); a7 += h2f(v7);
    }
    for (; e + 4 <= end; e += 4) {
        int s0 = es[e], s1 = es[e + 1], s2 = es[e + 2], s3 = es[e + 3];
        h4 v0 = *(const h4*)(h_in + (size_t)s0 * HID + c4);
        h4 v1 = *(const h4*)(h_in + (size_t)s1 * HID + c4);
        h4 v2 = *(const h4*)(h_in + (size_t)s2 * HID + c4);
        h4 v3 = *(const h4*)(h_in + (size_t)s3 * HID + c4);
        a0 += h2f(v0); a1 += h2f(v1); a2 += h2f(v2); a3 += h2f(v3);
    }
    for (; e < end; ++e)
        a0 += h2f(*(const h4*)(h_in + (size_t)es[e] * HID + c4));
    f4 t = ((a0 + a1) + (a2 + a3)) + ((a4 + a5) + (a6 + a7));
    *(h4*)(agg + (size_t)node * HID + c4) = f2h(t);
}

// MFMA GEMM, W-in-registers: wave owns a 16-j tile, loops 8 node-tiles.
// __launch_bounds__(256, 4): min 4 waves/EU -> <=128 VGPR cap. W fragments (64
// VGPR) must stay RESIDENT -- round-14 showed VGPR_Count=32: compiler had
// rematerialized the W loads into the ntile loop (400 MB L2 fan-in). asm pins
// below block that rematerialization.
__global__ __launch_bounds__(256, 4) void k_gemm_mfma(
    const _Float16* __restrict__ agg, const _Float16* __restrict__ h_in,
    _Float16* __restrict__ h_out,
    const _Float16* __restrict__ wT,   // [2][HID][HID] (j,k) for this layer
    const float* __restrict__ b_rel) {
    const int wave = (blockIdx.x << 2) + (threadIdx.x >> 6);  // 0..6255
    const int lane = threadIdx.x & 63;
    const int g = wave >> 3;       // ntile group 0..781
    const int jt = wave & 7;
    const int row = lane & 15;
    const int kg = lane >> 4;      // 0..3
    const int j0 = jt << 4;
    const int j = j0 + row;
    const float b = b_rel[j];

    const _Float16* wrP = wT + (size_t)(j0 + row) * HID + (kg << 3);
    const _Float16* woP = wT + (size_t)(HID + j0 + row) * HID + (kg << 3);
    f16x8 bR0 = *(const f16x8*)(wrP + 0);
    f16x8 bR1 = *(const f16x8*)(wrP + 32);
    f16x8 bR2 = *(const f16x8*)(wrP + 64);
    f16x8 bR3 = *(const f16x8*)(wrP + 96);
    f16x8 bO0 = *(const f16x8*)(woP + 0);
    f16x8 bO1 = *(const f16x8*)(woP + 32);
    f16x8 bO2 = *(const f16x8*)(woP + 64);
    f16x8 bO3 = *(const f16x8*)(woP + 96);
    // Pin W fragments in registers: forbid rematerialization/spill of the loads.
    asm volatile("" : "+v"(bR0), "+v"(bR1), "+v"(bR2), "+v"(bR3),
                      "+v"(bO0), "+v"(bO1), "+v"(bO2), "+v"(bO3));

    const int ntBeg = g * NTPW;
    const int ntEnd = (ntBeg + NTPW < NTILES) ? ntBeg + NTPW : NTILES;
    for (int nt = ntBeg; nt < ntEnd; ++nt) {
        const int node0 = nt << 4;
        const _Float16* aP = agg  + (size_t)(node0 + row) * HID + (kg << 3);
        const _Float16* hP = h_in + (size_t)(node0 + row) * HID + (kg << 3);
        f32x4 acc = {0.f, 0.f, 0.f, 0.f};
        acc = __builtin_amdgcn_mfma_f32_16x16x32_f16(*(const f16x8*)(aP + 0),  bR0, acc, 0, 0, 0);
        acc = __builtin_amdgcn_mfma_f32_16x16x32_f16(*(const f16x8*)(hP + 0),  bO0, acc, 0, 0, 0);
        acc = __builtin_amdgcn_mfma_f32_16x16x32_f16(*(const f16x8*)(aP + 32), bR1, acc, 0, 0, 0);
        acc = __builtin_amdgcn_mfma_f32_16x16x32_f16(*(const f16x8*)(hP + 32), bO1, acc, 0, 0, 0);
        acc = __builtin_amdgcn_mfma_f32_16x16x32_f16(*(const f16x8*)(aP + 64), bR2, acc, 0, 0, 0);
        acc = __builtin_amdgcn_mfma_f32_16x16x32_f16(*(const f16x8*)(hP + 64), bO2, acc, 0, 0, 0);
        acc = __builtin_amdgcn_mfma_f32_16x16x32_f16(*(const f16x8*)(aP + 96), bR3, acc, 0, 0, 0);
        acc = __builtin_amdgcn_mfma_f32_16x16x32_f16(*(const f16x8*)(hP + 96), bO3, acc, 0, 0, 0);
#pragma unroll
        for (int r = 0; r < 4; ++r) {
            float v = atanf(acc[r] + b);
            h_out[(size_t)(node0 + (kg << 2) + r) * HID + j] = (_Float16)v;
        }
    }
}

// Pool stage 1: per (graph, segment) partial sums over fp16 h -> fp32 part
__global__ __launch_bounds__(256) void k_pool1(
    const _Float16* __restrict__ h, const int* __restrict__ batch,
    float* __restrict__ part) {
    __shared__ float sm[2][HID];
    const int b = blockIdx.x;
    const int g = b >> 3, s = b & (SEG - 1);
    const int j = threadIdx.x & 127;
    const int half = threadIdx.x >> 7;

    int lo = 0, hi = N_NODES_C;
    while (lo < hi) { int mid = (lo + hi) >> 1; if (batch[mid] < g) lo = mid + 1; else hi = mid; }
    int start = lo;
    hi = N_NODES_C;
    while (lo < hi) { int mid = (lo + hi) >> 1; if (batch[mid] < g + 1) lo = mid + 1; else hi = mid; }
    int end = lo;
    int len = end - start;
    int s0 = start + (int)((long long)len * s / SEG);
    int s1 = start + (int)((long long)len * (s + 1) / SEG);

    float acc = 0.f;
    for (int i = s0 + half; i < s1; i += 2) acc += (float)h[(size_t)i * HID + j];
    sm[half][j] = acc;
    __syncthreads();
    if (threadIdx.x < HID) part[(size_t)b * HID + j] = sm[0][j] + sm[1][j];
}

// Pool stage 2 + head
__global__ __launch_bounds__(128) void k_head(
    const float* __restrict__ part, const float* __restrict__ W_out,
    const float* __restrict__ b_out, float* __restrict__ out) {
    __shared__ float sf[HID];
    const int g = blockIdx.x;
    const int j = threadIdx.x;
    float v = 0.f;
    for (int s = 0; s < SEG; ++s) v += part[(size_t)(g * SEG + s) * HID + j];
    sf[j] = v;
    __syncthreads();
    if (j < OUTD) {
        float a = b_out[j];
        for (int k = 0; k < HID; ++k) a += sf[k] * W_out[k * OUTD + j];
        out[g * OUTD + j] = 1.f / (1.f + expf(-a));
    }
}

extern "C" void kernel_launch(void* const* d_in, const int* in_sizes, int n_in,
                              void* d_out, int out_size, void* d_ws, size_t ws_size,
                              hipStream_t stream) {
    const float* x      = (const float*)d_in[0];
    const int*   ei     = (const int*)d_in[1];
    const int*   src    = ei;
    const int*   dst    = ei + N_EDGES_C;
    const int*   batch  = (const int*)d_in[2];
    const float* W_rel  = (const float*)d_in[3];
    const float* b_rel  = (const float*)d_in[4];
    const float* W_root = (const float*)d_in[5];
    const float* W_out  = (const float*)d_in[6];
    const float* b_out  = (const float*)d_in[7];
    float* out = (float*)d_out;

    char* ws = (char*)d_ws;
    size_t off = 0;
    auto alloc = [&](size_t bytes) { void* p = ws + off; off = align_up(off + bytes, 256); return p; };
    _Float16* xh    = (_Float16*)alloc((size_t)N_NODES_C * HID * 2);
    _Float16* h1h   = (_Float16*)alloc((size_t)N_NODES_C * HID * 2);
    _Float16* agg16 = (_Float16*)alloc((size_t)N_NODES_C * HID * 2);
    _Float16* wT    = (_Float16*)alloc((size_t)3 * 2 * HID * HID * 2);
    int*   offsets = (int*)alloc((size_t)(N_NODES_C + 1) * sizeof(int));
    int*   es      = (int*)alloc((size_t)N_EDGES_C * sizeof(int));
    unsigned* tmp  = (unsigned*)alloc((size_t)N_EDGES_C * sizeof(unsigned));
    int*   bhist   = (int*)alloc(NBUCK * sizeof(int));
    int*   bbase   = (int*)alloc((NBUCK + 1) * sizeof(int));
    int*   bcursor = (int*)alloc(NBUCK * sizeof(int));
    float* part    = (float*)alloc((size_t)N_GRAPHS_C * SEG * HID * sizeof(float));

    const int gather_blocks = N_NODES_C / 8;          // 12500
    const int mfma_blocks = NGRP * 8 / 4;             // 782*8 waves / 4 = 1564
    const int scat_blocks = (N_EDGES_C + CHUNK - 1) / CHUNK;
    const size_t WTL = (size_t)2 * HID * HID;

    // ---- weight prep + x -> fp16 ----
    k_wprep<<<768, 128, 0, stream>>>(W_rel, W_root, wT);
    k_cvt<<<(N_NODES_C * HID) / 4 / 256, 256, 0, stream>>>(x, xh);

    // ---- CSR build: bucket sort, all global scatter staged through LDS ----
    k_zeroB<<<1, 256, 0, stream>>>(bhist);
    k_hist1<<<1024, 256, 0, stream>>>(dst, bhist);
    k_bscan<<<1, 256, 0, stream>>>(bhist, bbase, bcursor);
    k_scatter1<<<scat_blocks, 256, 0, stream>>>(src, dst, bcursor, tmp);
    k_sort2<<<NBUCK, 256, 0, stream>>>(tmp, bbase, offsets, es);

    // ---- 3 GraphConv layers: gather (latency-opt) + MFMA gemm (W-in-reg) ----
    k_gather<<<gather_blocks, 256, 0, stream>>>(xh, agg16, offsets, es);
    k_gemm_mfma<<<mfma_blocks, 256, 0, stream>>>(agg16, xh, h1h, wT + 0 * WTL, b_rel + 0 * HID);
    k_gather<<<gather_blocks, 256, 0, stream>>>(h1h, agg16, offsets, es);
    k_gemm_mfma<<<mfma_blocks, 256, 0, stream>>>(agg16, h1h, xh, wT + 1 * WTL, b_rel + 1 * HID);
    k_gather<<<gather_blocks, 256, 0, stream>>>(xh, agg16, offsets, es);
    k_gemm_mfma<<<mfma_blocks, 256, 0, stream>>>(agg16, xh, h1h, wT + 2 * WTL, b_rel + 2 * HID);

    // ---- pool + head ----
    k_pool1<<<N_GRAPHS_C * SEG, 256, 0, stream>>>(h1h, batch, part);
    k_head<<<N_GRAPHS_C, 128, 0, stream>>>(part, W_out, b_out, out);
}